// Round 8
// baseline (7412.600 us; speedup 1.0000x reference)
//
#include <hip/hip_runtime.h>

using bf16x8 = __attribute__((ext_vector_type(8))) __bf16;
using f32x4  = __attribute__((ext_vector_type(4))) float;

#define C_ 64
#define S_ 128
#define H_ 2048
#define M_ 8192

__device__ __forceinline__ unsigned short f2bf(float f) {
  unsigned u = __float_as_uint(f);
  u = u + 0x7fffu + ((u >> 16) & 1u);   // RNE
  return (unsigned short)(u >> 16);
}
__device__ __forceinline__ float bf2f(unsigned short h) {
  return __uint_as_float(((unsigned)h) << 16);
}

// async global->LDS, 16 B per lane; LDS dest = uniform base + lane*16
__device__ __forceinline__ void glds16(const unsigned short* g, unsigned short* l) {
  __builtin_amdgcn_global_load_lds(
      (const __attribute__((address_space(1))) void*)g,
      (__attribute__((address_space(3))) void*)l, 16, 0, 0);
}

// ---- fused: split x (blocks 0..16383) | split+transpose W (16384..17407) | zero G ----
__global__ void k_split_all(const float* __restrict__ x,
                            unsigned short* __restrict__ xh,
                            unsigned short* __restrict__ xl,
                            const float* __restrict__ W,
                            unsigned short* __restrict__ Wth,
                            unsigned short* __restrict__ Wtl,
                            float* __restrict__ G) {
  __shared__ float Ts[64][68];
  const int b = blockIdx.x;
  const int t = threadIdx.x;
  if (b < 16384) {
    int idx = b * 256 + t;
    float4 v = ((const float4*)x)[idx];
    float a[4] = {v.x, v.y, v.z, v.w};
    unsigned short h[4], l[4];
#pragma unroll
    for (int q = 0; q < 4; ++q) {
      h[q] = f2bf(a[q]);
      l[q] = f2bf(a[q] - bf2f(h[q]));
    }
    ((ushort4*)xh)[idx] = make_ushort4(h[0], h[1], h[2], h[3]);
    ((ushort4*)xl)[idx] = make_ushort4(l[0], l[1], l[2], l[3]);
  } else if (b < 17408) {
    const int bb = b - 16384;
    const int k0 = (bb & 31) * 64, n0 = (bb >> 5) * 64;
#pragma unroll
    for (int p = 0; p < 4; ++p) {
      int idx = t + p * 256;
      int r = idx >> 4, c4 = (idx & 15) * 4;
      *(float4*)&Ts[r][c4] = *(const float4*)(W + (size_t)(k0 + r) * H_ + n0 + c4);
    }
    __syncthreads();
#pragma unroll
    for (int p = 0; p < 4; ++p) {
      int idx = t + p * 256;
      int rr = idx >> 4, cc = (idx & 15) * 4;   // rr = n-local, cc = k-local
      unsigned short h[4], l[4];
#pragma unroll
      for (int q = 0; q < 4; ++q) {
        float f = Ts[cc + q][rr];
        h[q] = f2bf(f);
        l[q] = f2bf(f - bf2f(h[q]));
      }
      size_t o = (size_t)(n0 + rr) * H_ + k0 + cc;
      *(ushort4*)(Wth + o) = make_ushort4(h[0], h[1], h[2], h[3]);
      *(ushort4*)(Wtl + o) = make_ushort4(l[0], l[1], l[2], l[3]);
    }
  } else {
    const int bb = b - 17408;   // 1024 blocks * 256 threads * 16 B = 4 MiB
    ((float4*)G)[bb * 256 + t] = (float4){0.f, 0.f, 0.f, 0.f};
  }
}

// ------- 3-term split-bf16 MFMA GEMM: A reg-double-buffered from global,
//         B LDS-double-buffered via glds16; ONE barrier per K-iter. -------
// All prefetches (A regs + B glds) for iter k+1 are issued at the TOP of iter k
// -> a full MFMA phase (~3000 cyc) of slack before the end-of-iter barrier
// drain. R7's failure (zero issue-to-use slack on A) is removed; R5's proven
// XOR-swizzle B layout kept (R7 measured 0 conflicts).
__global__ __launch_bounds__(256, 3) void k_gemm3(
    const unsigned short* __restrict__ Ah, const unsigned short* __restrict__ Al,
    const unsigned short* __restrict__ Bh, const unsigned short* __restrict__ Bl,
    unsigned short* __restrict__ Eh, unsigned short* __restrict__ El) {
  __shared__ unsigned short sBh[2 * 4096], sBl[2 * 4096];
  const int t = threadIdx.x;
  const int bn = blockIdx.x, bm = blockIdx.y;
  const int lane = t & 63, wid = t >> 6;
  const int wm = wid >> 1, wn = wid & 1;
  const int l16 = lane & 15, quad = lane >> 4;

  // ---- B staging geometry (proven) ----
  const int rl = lane >> 2;
  const int gg = (lane & 3) ^ ((rl >> 1) & 3);
  const int c0 = wid * 2, c1 = wid * 2 + 1;
  const unsigned short* gBh0 = Bh + (size_t)(bn * 128 + c0 * 16 + rl) * H_ + gg * 8;
  const unsigned short* gBh1 = Bh + (size_t)(bn * 128 + c1 * 16 + rl) * H_ + gg * 8;
  const unsigned short* gBl0 = Bl + (size_t)(bn * 128 + c0 * 16 + rl) * H_ + gg * 8;
  const unsigned short* gBl1 = Bl + (size_t)(bn * 128 + c1 * 16 + rl) * H_ + gg * 8;

  // ---- A direct-load bases (frag i: row = bm*128 + wm*64 + i*16 + l16) ----
  const unsigned short* gA_h[4];
  const unsigned short* gA_l[4];
#pragma unroll
  for (int i = 0; i < 4; ++i) {
    const size_t ro = (size_t)(bm * 128 + wm * 64 + i * 16 + l16) * H_ + quad * 8;
    gA_h[i] = Ah + ro;
    gA_l[i] = Al + ro;
  }

  const int swz = ((l16 >> 1) & 3);
  const int colq = ((quad ^ swz) * 8);

  f32x4 acc[4][4];
#pragma unroll
  for (int i = 0; i < 4; ++i)
#pragma unroll
    for (int j = 0; j < 4; ++j) acc[i][j] = (f32x4)0.f;

  // A register double-buffer
  bf16x8 ah[2][4], al[2][4];

  // prologue: A(0) -> buf0, B(0) -> LDS buf0
#pragma unroll
  for (int i = 0; i < 4; ++i) {
    ah[0][i] = *(const bf16x8*)(gA_h[i]);
    al[0][i] = *(const bf16x8*)(gA_l[i]);
  }
  glds16(gBh0, sBh + c0 * 512);
  glds16(gBh1, sBh + c1 * 512);
  glds16(gBl0, sBl + c0 * 512);
  glds16(gBl1, sBl + c1 * 512);
  __syncthreads();

  for (int k0 = 0; k0 < 64; ++k0) {
    const int cur = k0 & 1;
    const int bo = cur * 4096;

    if (k0 + 1 < 64) {
      const int kn = (k0 + 1) * 32;
      // A(k+1) -> other reg buffer (full-iter slack before use)
#pragma unroll
      for (int i = 0; i < 4; ++i) {
        ah[cur ^ 1][i] = *(const bf16x8*)(gA_h[i] + kn);
        al[cur ^ 1][i] = *(const bf16x8*)(gA_l[i] + kn);
      }
      // B(k+1) -> other LDS buffer
      const int nb = 4096 - bo;
      glds16(gBh0 + kn, sBh + nb + c0 * 512);
      glds16(gBh1 + kn, sBh + nb + c1 * 512);
      glds16(gBl0 + kn, sBl + nb + c0 * 512);
      glds16(gBl1 + kn, sBl + nb + c1 * 512);
    }

    // compute iter k from A regs (prefetched last iter) + B LDS buf cur
#pragma unroll
    for (int j = 0; j < 4; ++j) {
      const int rb = bo + (wn * 64 + j * 16 + l16) * 32;
      bf16x8 bh = *(const bf16x8*)&sBh[rb + colq];
      bf16x8 bl = *(const bf16x8*)&sBl[rb + colq];
#pragma unroll
      for (int i = 0; i < 4; ++i) {
        acc[i][j] = __builtin_amdgcn_mfma_f32_16x16x32_bf16(ah[cur][i], bh, acc[i][j], 0, 0, 0);
        acc[i][j] = __builtin_amdgcn_mfma_f32_16x16x32_bf16(ah[cur][i], bl, acc[i][j], 0, 0, 0);
        acc[i][j] = __builtin_amdgcn_mfma_f32_16x16x32_bf16(al[cur][i], bh, acc[i][j], 0, 0, 0);
      }
    }
    __syncthreads();   // drain covered by the MFMA phase above
  }

#pragma unroll
  for (int i = 0; i < 4; ++i) {
    const int row0 = bm * 128 + wm * 64 + i * 16 + quad * 4;
#pragma unroll
    for (int j = 0; j < 4; ++j) {
      const int col = bn * 128 + wn * 64 + j * 16 + l16;
#pragma unroll
      for (int r = 0; r < 4; ++r) {
        float v = acc[i][j][r];
        unsigned short hh = f2bf(v);
        unsigned short ll = f2bf(v - bf2f(hh));
        Eh[(size_t)(row0 + r) * H_ + col] = hh;
        El[(size_t)(row0 + r) * H_ + col] = ll;
      }
    }
  }
}

// ---- MFMA Gram: G[c] += Eh*Eh^T + Eh*El^T + El*Eh^T over a 256-wide K chunk ----
__global__ __launch_bounds__(256, 4) void k_gram_mfma(
    const unsigned short* __restrict__ Eh, const unsigned short* __restrict__ El,
    float* __restrict__ G) {
  __shared__ unsigned short sH[128 * 32], sL[128 * 32];
  const int t = threadIdx.x;
  const int kc = blockIdx.x;   // 0..7, K chunk of 256
  const int cc = blockIdx.y;   // capsule
  const int lane = t & 63, wid = t >> 6;
  const int wm = wid >> 1, wn = wid & 1;
  const int l16 = lane & 15, quad = lane >> 4;

  const int rl = lane >> 2;
  const int gg = (lane & 3) ^ ((rl >> 1) & 3);
  const int c0 = wid * 2, c1 = c0 + 1;
  const size_t kbase = (size_t)kc * 256 + gg * 8;
  const unsigned short* gH0 = Eh + (size_t)(cc * 128 + c0 * 16 + rl) * H_ + kbase;
  const unsigned short* gH1 = Eh + (size_t)(cc * 128 + c1 * 16 + rl) * H_ + kbase;
  const unsigned short* gL0 = El + (size_t)(cc * 128 + c0 * 16 + rl) * H_ + kbase;
  const unsigned short* gL1 = El + (size_t)(cc * 128 + c1 * 16 + rl) * H_ + kbase;
  unsigned short* lH0 = sH + c0 * 512;
  unsigned short* lH1 = sH + c1 * 512;
  unsigned short* lL0 = sL + c0 * 512;
  unsigned short* lL1 = sL + c1 * 512;

  const int swz = ((l16 >> 1) & 3);
  const int colq = ((quad ^ swz) * 8);

  f32x4 acc[4][4];
#pragma unroll
  for (int i = 0; i < 4; ++i)
#pragma unroll
    for (int j = 0; j < 4; ++j) acc[i][j] = (f32x4)0.f;

  for (int k0 = 0; k0 < 256; k0 += 32) {
    __syncthreads();
    glds16(gH0 + k0, lH0);
    glds16(gH1 + k0, lH1);
    glds16(gL0 + k0, lL0);
    glds16(gL1 + k0, lL1);
    __syncthreads();

    bf16x8 ah[4], al[4], bh[4], bl[4];
#pragma unroll
    for (int i = 0; i < 4; ++i) {
      const int ra = (wm * 64 + i * 16 + l16) * 32;
      const int rb = (wn * 64 + i * 16 + l16) * 32;
      ah[i] = *(const bf16x8*)&sH[ra + colq];
      al[i] = *(const bf16x8*)&sL[ra + colq];
      bh[i] = *(const bf16x8*)&sH[rb + colq];
      bl[i] = *(const bf16x8*)&sL[rb + colq];
    }
#pragma unroll
    for (int i = 0; i < 4; ++i)
#pragma unroll
      for (int j = 0; j < 4; ++j) {
        acc[i][j] = __builtin_amdgcn_mfma_f32_16x16x32_bf16(ah[i], bh[j], acc[i][j], 0, 0, 0);
        acc[i][j] = __builtin_amdgcn_mfma_f32_16x16x32_bf16(ah[i], bl[j], acc[i][j], 0, 0, 0);
        acc[i][j] = __builtin_amdgcn_mfma_f32_16x16x32_bf16(al[i], bh[j], acc[i][j], 0, 0, 0);
      }
  }

  float* Gc = G + (size_t)cc * S_ * S_;
#pragma unroll
  for (int i = 0; i < 4; ++i) {
    const int row0 = wm * 64 + i * 16 + quad * 4;
#pragma unroll
    for (int j = 0; j < 4; ++j) {
      const int col = wn * 64 + j * 16 + l16;
#pragma unroll
      for (int r = 0; r < 4; ++r)
        atomicAdd(&Gc[(row0 + r) * S_ + col], acc[i][j][r]);
    }
  }
}

// ---- fused routing + projection: each block redoes its capsule's routing ----
__global__ void k_out2(const unsigned short* __restrict__ Eh,
                       const unsigned short* __restrict__ El,
                       const float* __restrict__ G, float* __restrict__ out) {
  const int c = blockIdx.y;
  const int s = threadIdx.x & 127;
  __shared__ float dsh[128];
  __shared__ float red[128];
  __shared__ float wsh[128];
  const float* Gc = G + (size_t)c * S_ * S_;
  float b = 0.f;
  for (int it = 0; it < 3; ++it) {
    red[s] = b; __syncthreads();
    for (int off = 64; off > 0; off >>= 1) {
      if (s < off) red[s] = fmaxf(red[s], red[s + off]);
      __syncthreads();
    }
    float mx = red[0]; __syncthreads();
    float ev = expf(b - mx);
    red[s] = ev; __syncthreads();
    for (int off = 64; off > 0; off >>= 1) {
      if (s < off) red[s] = red[s] + red[s + off];
      __syncthreads();
    }
    float Z = red[0]; __syncthreads();
    float d = ev / Z;
    dsh[s] = d; __syncthreads();
    float y = 0.f;   // (G d)_s via symmetric-column reads
#pragma unroll 8
    for (int j = 0; j < S_; ++j) y = fmaf(Gc[j * S_ + s], dsh[j], y);
    red[s] = d * y; __syncthreads();
    for (int off = 64; off > 0; off >>= 1) {
      if (s < off) red[s] = red[s] + red[s + off];
      __syncthreads();
    }
    float sq = red[0]; __syncthreads();
    float coeff = sq / (1.f + sq) / sqrtf(sq + 1e-9f);
    if (it == 2) wsh[s] = coeff * d;
    else b += coeff * y;
  }
  __syncthreads();

  // projection: out[c,h] = sum_s wsh[s] * (Eh+El)[c,s,h], 2 h per thread
  const int h2 = blockIdx.x * 256 + threadIdx.x;   // dword index, grid.x = 4
  const unsigned* Ph = (const unsigned*)(Eh + (size_t)c * S_ * H_) + h2;
  const unsigned* Pl = (const unsigned*)(El + (size_t)c * S_ * H_) + h2;
  float a0 = 0.f, a1 = 0.f;
#pragma unroll 8
  for (int ss = 0; ss < S_; ++ss) {
    unsigned uh = Ph[(size_t)ss * (H_ / 2)];
    unsigned ul = Pl[(size_t)ss * (H_ / 2)];
    a0 = fmaf(wsh[ss], bf2f((unsigned short)uh) + bf2f((unsigned short)ul), a0);
    a1 = fmaf(wsh[ss], bf2f((unsigned short)(uh >> 16)) + bf2f((unsigned short)(ul >> 16)), a1);
  }
  ((float2*)(out + (size_t)c * H_))[h2] = make_float2(a0, a1);
}

extern "C" void kernel_launch(void* const* d_in, const int* in_sizes, int n_in,
                              void* d_out, int out_size, void* d_ws, size_t ws_size,
                              hipStream_t stream) {
  (void)in_sizes; (void)n_in; (void)out_size; (void)ws_size;
  const float* x = (const float*)d_in[0];
  const float* W = (const float*)d_in[1];
  float* out = (float*)d_out;
  char* ws = (char*)d_ws;

  unsigned short* xh  = (unsigned short*)(ws);                 // 32 MiB
  unsigned short* xl  = (unsigned short*)(ws + 33554432);      // 32 MiB
  unsigned short* Wth = (unsigned short*)(ws + 67108864);      // 8 MiB
  unsigned short* Wtl = (unsigned short*)(ws + 75497472);      // 8 MiB
  unsigned short* Eh  = (unsigned short*)(ws + 83886080);      // 32 MiB
  unsigned short* El  = (unsigned short*)(ws + 117440512);     // 32 MiB
  float*          G   = (float*)(ws + 150994944);              // 4 MiB

  k_split_all<<<dim3(18432), 256, 0, stream>>>(x, xh, xl, W, Wth, Wtl, G);
  k_gemm3<<<dim3(16, 64), 256, 0, stream>>>(xh, xl, Wth, Wtl, Eh, El);
  k_gram_mfma<<<dim3(8, 64), 256, 0, stream>>>(Eh, El, G);
  k_out2<<<dim3(4, 64), 256, 0, stream>>>(Eh, El, G, out);
}

// Round 9
// 552.917 us; speedup vs baseline: 13.4063x; 13.4063x over previous
//
#include <hip/hip_runtime.h>

using bf16x8 = __attribute__((ext_vector_type(8))) __bf16;
using f32x4  = __attribute__((ext_vector_type(4))) float;

#define C_ 64
#define S_ 128
#define H_ 2048
#define M_ 8192

__device__ __forceinline__ unsigned short f2bf(float f) {
  unsigned u = __float_as_uint(f);
  u = u + 0x7fffu + ((u >> 16) & 1u);   // RNE
  return (unsigned short)(u >> 16);
}
__device__ __forceinline__ float bf2f(unsigned short h) {
  return __uint_as_float(((unsigned)h) << 16);
}

// async global->LDS, 16 B per lane; LDS dest = uniform base + lane*16
__device__ __forceinline__ void glds16(const unsigned short* g, unsigned short* l) {
  __builtin_amdgcn_global_load_lds(
      (const __attribute__((address_space(1))) void*)g,
      (__attribute__((address_space(3))) void*)l, 16, 0, 0);
}

// ---- fused: split x (blocks 0..16383) | split+transpose W (16384..17407) | zero G ----
__global__ void k_split_all(const float* __restrict__ x,
                            unsigned short* __restrict__ xh,
                            unsigned short* __restrict__ xl,
                            const float* __restrict__ W,
                            unsigned short* __restrict__ Wth,
                            unsigned short* __restrict__ Wtl,
                            float* __restrict__ G) {
  __shared__ float Ts[64][68];
  const int b = blockIdx.x;
  const int t = threadIdx.x;
  if (b < 16384) {
    int idx = b * 256 + t;
    float4 v = ((const float4*)x)[idx];
    float a[4] = {v.x, v.y, v.z, v.w};
    unsigned short h[4], l[4];
#pragma unroll
    for (int q = 0; q < 4; ++q) {
      h[q] = f2bf(a[q]);
      l[q] = f2bf(a[q] - bf2f(h[q]));
    }
    ((ushort4*)xh)[idx] = make_ushort4(h[0], h[1], h[2], h[3]);
    ((ushort4*)xl)[idx] = make_ushort4(l[0], l[1], l[2], l[3]);
  } else if (b < 17408) {
    const int bb = b - 16384;
    const int k0 = (bb & 31) * 64, n0 = (bb >> 5) * 64;
#pragma unroll
    for (int p = 0; p < 4; ++p) {
      int idx = t + p * 256;
      int r = idx >> 4, c4 = (idx & 15) * 4;
      *(float4*)&Ts[r][c4] = *(const float4*)(W + (size_t)(k0 + r) * H_ + n0 + c4);
    }
    __syncthreads();
#pragma unroll
    for (int p = 0; p < 4; ++p) {
      int idx = t + p * 256;
      int rr = idx >> 4, cc = (idx & 15) * 4;   // rr = n-local, cc = k-local
      unsigned short h[4], l[4];
#pragma unroll
      for (int q = 0; q < 4; ++q) {
        float f = Ts[cc + q][rr];
        h[q] = f2bf(f);
        l[q] = f2bf(f - bf2f(h[q]));
      }
      size_t o = (size_t)(n0 + rr) * H_ + k0 + cc;
      *(ushort4*)(Wth + o) = make_ushort4(h[0], h[1], h[2], h[3]);
      *(ushort4*)(Wtl + o) = make_ushort4(l[0], l[1], l[2], l[3]);
    }
  } else {
    const int bb = b - 17408;   // 1024 blocks * 256 threads * 16 B = 4 MiB
    ((float4*)G)[bb * 256 + t] = (float4){0.f, 0.f, 0.f, 0.f};
  }
}

// ------- 3-term split-bf16 MFMA GEMM: A reg-dbuf (STATIC indices via unroll-2),
//         B LDS-dbuf via glds16; ONE barrier per K-sub-iter. -------
// R8's scratch-spill bug (dynamic ah[cur][i] indexing -> arrays demoted to
// scratch, VGPR=84, 2.5 GB HBM traffic) fixed by manual unroll-by-2: all
// register-array indices compile-time. Prefetches for k+1 issue at the top of
// sub-iter k -> full MFMA phase (~3000 cyc) of slack before the barrier drain.
__global__ __launch_bounds__(256, 3) void k_gemm3(
    const unsigned short* __restrict__ Ah, const unsigned short* __restrict__ Al,
    const unsigned short* __restrict__ Bh, const unsigned short* __restrict__ Bl,
    unsigned short* __restrict__ Eh, unsigned short* __restrict__ El) {
  __shared__ unsigned short sBh[2 * 4096], sBl[2 * 4096];
  const int t = threadIdx.x;
  const int bn = blockIdx.x, bm = blockIdx.y;
  const int lane = t & 63, wid = t >> 6;
  const int wm = wid >> 1, wn = wid & 1;
  const int l16 = lane & 15, quad = lane >> 4;

  // ---- B staging geometry (proven: 0 conflicts R5/R7) ----
  const int rl = lane >> 2;
  const int gg = (lane & 3) ^ ((rl >> 1) & 3);
  const int c0 = wid * 2, c1 = wid * 2 + 1;
  const unsigned short* gBh0 = Bh + (size_t)(bn * 128 + c0 * 16 + rl) * H_ + gg * 8;
  const unsigned short* gBh1 = Bh + (size_t)(bn * 128 + c1 * 16 + rl) * H_ + gg * 8;
  const unsigned short* gBl0 = Bl + (size_t)(bn * 128 + c0 * 16 + rl) * H_ + gg * 8;
  const unsigned short* gBl1 = Bl + (size_t)(bn * 128 + c1 * 16 + rl) * H_ + gg * 8;

  // ---- A direct-load bases (frag i: row = bm*128 + wm*64 + i*16 + l16) ----
  const unsigned short* gA_h[4];
  const unsigned short* gA_l[4];
#pragma unroll
  for (int i = 0; i < 4; ++i) {
    const size_t ro = (size_t)(bm * 128 + wm * 64 + i * 16 + l16) * H_ + quad * 8;
    gA_h[i] = Ah + ro;
    gA_l[i] = Al + ro;
  }

  const int swz = ((l16 >> 1) & 3);
  const int colq = ((quad ^ swz) * 8);

  f32x4 acc[4][4];
#pragma unroll
  for (int i = 0; i < 4; ++i)
#pragma unroll
    for (int j = 0; j < 4; ++j) acc[i][j] = (f32x4)0.f;

  // A register double-buffer: STATIC arrays (unroll-2 keeps indices constant)
  bf16x8 ah0[4], al0[4], ah1[4], al1[4];

  // prologue: A(0) -> buf0, B(0) -> LDS buf0
#pragma unroll
  for (int i = 0; i < 4; ++i) {
    ah0[i] = *(const bf16x8*)(gA_h[i]);
    al0[i] = *(const bf16x8*)(gA_l[i]);
  }
  glds16(gBh0, sBh + c0 * 512);
  glds16(gBh1, sBh + c1 * 512);
  glds16(gBl0, sBl + c0 * 512);
  glds16(gBl1, sBl + c1 * 512);
  __syncthreads();

  for (int k0 = 0; k0 < 64; k0 += 2) {
    // ---- even sub-iter: compute buf0, prefetch k0+1 into buf1 ----
    {
      const int kn = (k0 + 1) * 32;
#pragma unroll
      for (int i = 0; i < 4; ++i) {
        ah1[i] = *(const bf16x8*)(gA_h[i] + kn);
        al1[i] = *(const bf16x8*)(gA_l[i] + kn);
      }
      glds16(gBh0 + kn, sBh + 4096 + c0 * 512);
      glds16(gBh1 + kn, sBh + 4096 + c1 * 512);
      glds16(gBl0 + kn, sBl + 4096 + c0 * 512);
      glds16(gBl1 + kn, sBl + 4096 + c1 * 512);
#pragma unroll
      for (int j = 0; j < 4; ++j) {
        const int rb = (wn * 64 + j * 16 + l16) * 32;
        bf16x8 bh = *(const bf16x8*)&sBh[rb + colq];
        bf16x8 bl = *(const bf16x8*)&sBl[rb + colq];
#pragma unroll
        for (int i = 0; i < 4; ++i) {
          acc[i][j] = __builtin_amdgcn_mfma_f32_16x16x32_bf16(ah0[i], bh, acc[i][j], 0, 0, 0);
          acc[i][j] = __builtin_amdgcn_mfma_f32_16x16x32_bf16(ah0[i], bl, acc[i][j], 0, 0, 0);
          acc[i][j] = __builtin_amdgcn_mfma_f32_16x16x32_bf16(al0[i], bh, acc[i][j], 0, 0, 0);
        }
      }
      __syncthreads();
    }
    // ---- odd sub-iter: compute buf1, prefetch k0+2 into buf0 ----
    {
      if (k0 + 2 < 64) {
        const int kn = (k0 + 2) * 32;
#pragma unroll
        for (int i = 0; i < 4; ++i) {
          ah0[i] = *(const bf16x8*)(gA_h[i] + kn);
          al0[i] = *(const bf16x8*)(gA_l[i] + kn);
        }
        glds16(gBh0 + kn, sBh + c0 * 512);
        glds16(gBh1 + kn, sBh + c1 * 512);
        glds16(gBl0 + kn, sBl + c0 * 512);
        glds16(gBl1 + kn, sBl + c1 * 512);
      }
#pragma unroll
      for (int j = 0; j < 4; ++j) {
        const int rb = 4096 + (wn * 64 + j * 16 + l16) * 32;
        bf16x8 bh = *(const bf16x8*)&sBh[rb + colq];
        bf16x8 bl = *(const bf16x8*)&sBl[rb + colq];
#pragma unroll
        for (int i = 0; i < 4; ++i) {
          acc[i][j] = __builtin_amdgcn_mfma_f32_16x16x32_bf16(ah1[i], bh, acc[i][j], 0, 0, 0);
          acc[i][j] = __builtin_amdgcn_mfma_f32_16x16x32_bf16(ah1[i], bl, acc[i][j], 0, 0, 0);
          acc[i][j] = __builtin_amdgcn_mfma_f32_16x16x32_bf16(al1[i], bh, acc[i][j], 0, 0, 0);
        }
      }
      __syncthreads();
    }
  }

#pragma unroll
  for (int i = 0; i < 4; ++i) {
    const int row0 = bm * 128 + wm * 64 + i * 16 + quad * 4;
#pragma unroll
    for (int j = 0; j < 4; ++j) {
      const int col = bn * 128 + wn * 64 + j * 16 + l16;
#pragma unroll
      for (int r = 0; r < 4; ++r) {
        float v = acc[i][j][r];
        unsigned short hh = f2bf(v);
        unsigned short ll = f2bf(v - bf2f(hh));
        Eh[(size_t)(row0 + r) * H_ + col] = hh;
        El[(size_t)(row0 + r) * H_ + col] = ll;
      }
    }
  }
}

// ---- MFMA Gram: G[c] += Eh*Eh^T + Eh*El^T + El*Eh^T over a 256-wide K chunk ----
__global__ __launch_bounds__(256, 4) void k_gram_mfma(
    const unsigned short* __restrict__ Eh, const unsigned short* __restrict__ El,
    float* __restrict__ G) {
  __shared__ unsigned short sH[128 * 32], sL[128 * 32];
  const int t = threadIdx.x;
  const int kc = blockIdx.x;   // 0..7, K chunk of 256
  const int cc = blockIdx.y;   // capsule
  const int lane = t & 63, wid = t >> 6;
  const int wm = wid >> 1, wn = wid & 1;
  const int l16 = lane & 15, quad = lane >> 4;

  const int rl = lane >> 2;
  const int gg = (lane & 3) ^ ((rl >> 1) & 3);
  const int c0 = wid * 2, c1 = c0 + 1;
  const size_t kbase = (size_t)kc * 256 + gg * 8;
  const unsigned short* gH0 = Eh + (size_t)(cc * 128 + c0 * 16 + rl) * H_ + kbase;
  const unsigned short* gH1 = Eh + (size_t)(cc * 128 + c1 * 16 + rl) * H_ + kbase;
  const unsigned short* gL0 = El + (size_t)(cc * 128 + c0 * 16 + rl) * H_ + kbase;
  const unsigned short* gL1 = El + (size_t)(cc * 128 + c1 * 16 + rl) * H_ + kbase;
  unsigned short* lH0 = sH + c0 * 512;
  unsigned short* lH1 = sH + c1 * 512;
  unsigned short* lL0 = sL + c0 * 512;
  unsigned short* lL1 = sL + c1 * 512;

  const int swz = ((l16 >> 1) & 3);
  const int colq = ((quad ^ swz) * 8);

  f32x4 acc[4][4];
#pragma unroll
  for (int i = 0; i < 4; ++i)
#pragma unroll
    for (int j = 0; j < 4; ++j) acc[i][j] = (f32x4)0.f;

  for (int k0 = 0; k0 < 256; k0 += 32) {
    __syncthreads();
    glds16(gH0 + k0, lH0);
    glds16(gH1 + k0, lH1);
    glds16(gL0 + k0, lL0);
    glds16(gL1 + k0, lL1);
    __syncthreads();

    bf16x8 ah[4], al[4], bh[4], bl[4];
#pragma unroll
    for (int i = 0; i < 4; ++i) {
      const int ra = (wm * 64 + i * 16 + l16) * 32;
      const int rb = (wn * 64 + i * 16 + l16) * 32;
      ah[i] = *(const bf16x8*)&sH[ra + colq];
      al[i] = *(const bf16x8*)&sL[ra + colq];
      bh[i] = *(const bf16x8*)&sH[rb + colq];
      bl[i] = *(const bf16x8*)&sL[rb + colq];
    }
#pragma unroll
    for (int i = 0; i < 4; ++i)
#pragma unroll
      for (int j = 0; j < 4; ++j) {
        acc[i][j] = __builtin_amdgcn_mfma_f32_16x16x32_bf16(ah[i], bh[j], acc[i][j], 0, 0, 0);
        acc[i][j] = __builtin_amdgcn_mfma_f32_16x16x32_bf16(ah[i], bl[j], acc[i][j], 0, 0, 0);
        acc[i][j] = __builtin_amdgcn_mfma_f32_16x16x32_bf16(al[i], bh[j], acc[i][j], 0, 0, 0);
      }
  }

  float* Gc = G + (size_t)cc * S_ * S_;
#pragma unroll
  for (int i = 0; i < 4; ++i) {
    const int row0 = wm * 64 + i * 16 + quad * 4;
#pragma unroll
    for (int j = 0; j < 4; ++j) {
      const int col = wn * 64 + j * 16 + l16;
#pragma unroll
      for (int r = 0; r < 4; ++r)
        atomicAdd(&Gc[(row0 + r) * S_ + col], acc[i][j][r]);
    }
  }
}

// ---- fused routing + projection: each block redoes its capsule's routing ----
__global__ void k_out2(const unsigned short* __restrict__ Eh,
                       const unsigned short* __restrict__ El,
                       const float* __restrict__ G, float* __restrict__ out) {
  const int c = blockIdx.y;
  const int s = threadIdx.x & 127;
  __shared__ float dsh[128];
  __shared__ float red[128];
  __shared__ float wsh[128];
  const float* Gc = G + (size_t)c * S_ * S_;
  float b = 0.f;
  for (int it = 0; it < 3; ++it) {
    red[s] = b; __syncthreads();
    for (int off = 64; off > 0; off >>= 1) {
      if (s < off) red[s] = fmaxf(red[s], red[s + off]);
      __syncthreads();
    }
    float mx = red[0]; __syncthreads();
    float ev = expf(b - mx);
    red[s] = ev; __syncthreads();
    for (int off = 64; off > 0; off >>= 1) {
      if (s < off) red[s] = red[s] + red[s + off];
      __syncthreads();
    }
    float Z = red[0]; __syncthreads();
    float d = ev / Z;
    dsh[s] = d; __syncthreads();
    float y = 0.f;   // (G d)_s via symmetric-column reads
#pragma unroll 8
    for (int j = 0; j < S_; ++j) y = fmaf(Gc[j * S_ + s], dsh[j], y);
    red[s] = d * y; __syncthreads();
    for (int off = 64; off > 0; off >>= 1) {
      if (s < off) red[s] = red[s] + red[s + off];
      __syncthreads();
    }
    float sq = red[0]; __syncthreads();
    float coeff = sq / (1.f + sq) / sqrtf(sq + 1e-9f);
    if (it == 2) wsh[s] = coeff * d;
    else b += coeff * y;
  }
  __syncthreads();

  // projection: out[c,h] = sum_s wsh[s] * (Eh+El)[c,s,h], 2 h per thread
  const int h2 = blockIdx.x * 256 + threadIdx.x;   // dword index, grid.x = 4
  const unsigned* Ph = (const unsigned*)(Eh + (size_t)c * S_ * H_) + h2;
  const unsigned* Pl = (const unsigned*)(El + (size_t)c * S_ * H_) + h2;
  float a0 = 0.f, a1 = 0.f;
#pragma unroll 8
  for (int ss = 0; ss < S_; ++ss) {
    unsigned uh = Ph[(size_t)ss * (H_ / 2)];
    unsigned ul = Pl[(size_t)ss * (H_ / 2)];
    a0 = fmaf(wsh[ss], bf2f((unsigned short)uh) + bf2f((unsigned short)ul), a0);
    a1 = fmaf(wsh[ss], bf2f((unsigned short)(uh >> 16)) + bf2f((unsigned short)(ul >> 16)), a1);
  }
  ((float2*)(out + (size_t)c * H_))[h2] = make_float2(a0, a1);
}

extern "C" void kernel_launch(void* const* d_in, const int* in_sizes, int n_in,
                              void* d_out, int out_size, void* d_ws, size_t ws_size,
                              hipStream_t stream) {
  (void)in_sizes; (void)n_in; (void)out_size; (void)ws_size;
  const float* x = (const float*)d_in[0];
  const float* W = (const float*)d_in[1];
  float* out = (float*)d_out;
  char* ws = (char*)d_ws;

  unsigned short* xh  = (unsigned short*)(ws);                 // 32 MiB
  unsigned short* xl  = (unsigned short*)(ws + 33554432);      // 32 MiB
  unsigned short* Wth = (unsigned short*)(ws + 67108864);      // 8 MiB
  unsigned short* Wtl = (unsigned short*)(ws + 75497472);      // 8 MiB
  unsigned short* Eh  = (unsigned short*)(ws + 83886080);      // 32 MiB
  unsigned short* El  = (unsigned short*)(ws + 117440512);     // 32 MiB
  float*          G   = (float*)(ws + 150994944);              // 4 MiB

  k_split_all<<<dim3(18432), 256, 0, stream>>>(x, xh, xl, W, Wth, Wtl, G);
  k_gemm3<<<dim3(16, 64), 256, 0, stream>>>(xh, xl, Wth, Wtl, Eh, El);
  k_gram_mfma<<<dim3(8, 64), 256, 0, stream>>>(Eh, El, G);
  k_out2<<<dim3(4, 64), 256, 0, stream>>>(Eh, El, G, out);
}

// Round 10
// 369.991 us; speedup vs baseline: 20.0345x; 1.4944x over previous
//
#include <hip/hip_runtime.h>

using bf16x8 = __attribute__((ext_vector_type(8))) __bf16;
using f32x4  = __attribute__((ext_vector_type(4))) float;

#define C_ 64
#define S_ 128
#define H_ 2048
#define M_ 8192

__device__ __forceinline__ unsigned short f2bf(float f) {
  unsigned u = __float_as_uint(f);
  u = u + 0x7fffu + ((u >> 16) & 1u);   // RNE
  return (unsigned short)(u >> 16);
}
__device__ __forceinline__ float bf2f(unsigned short h) {
  return __uint_as_float(((unsigned)h) << 16);
}

// async global->LDS, 16 B per lane; LDS dest = uniform base + lane*16
__device__ __forceinline__ void glds16(const unsigned short* g, unsigned short* l) {
  __builtin_amdgcn_global_load_lds(
      (const __attribute__((address_space(1))) void*)g,
      (__attribute__((address_space(3))) void*)l, 16, 0, 0);
}

// ---- fused: split x (blocks 0..16383) | split+transpose W (16384..17407) | zero G ----
__global__ void k_split_all(const float* __restrict__ x,
                            unsigned short* __restrict__ xh,
                            unsigned short* __restrict__ xl,
                            const float* __restrict__ W,
                            unsigned short* __restrict__ Wth,
                            unsigned short* __restrict__ Wtl,
                            float* __restrict__ G) {
  __shared__ float Ts[64][68];
  const int b = blockIdx.x;
  const int t = threadIdx.x;
  if (b < 16384) {
    int idx = b * 256 + t;
    float4 v = ((const float4*)x)[idx];
    float a[4] = {v.x, v.y, v.z, v.w};
    unsigned short h[4], l[4];
#pragma unroll
    for (int q = 0; q < 4; ++q) {
      h[q] = f2bf(a[q]);
      l[q] = f2bf(a[q] - bf2f(h[q]));
    }
    ((ushort4*)xh)[idx] = make_ushort4(h[0], h[1], h[2], h[3]);
    ((ushort4*)xl)[idx] = make_ushort4(l[0], l[1], l[2], l[3]);
  } else if (b < 17408) {
    const int bb = b - 16384;
    const int k0 = (bb & 31) * 64, n0 = (bb >> 5) * 64;
#pragma unroll
    for (int p = 0; p < 4; ++p) {
      int idx = t + p * 256;
      int r = idx >> 4, c4 = (idx & 15) * 4;
      *(float4*)&Ts[r][c4] = *(const float4*)(W + (size_t)(k0 + r) * H_ + n0 + c4);
    }
    __syncthreads();
#pragma unroll
    for (int p = 0; p < 4; ++p) {
      int idx = t + p * 256;
      int rr = idx >> 4, cc = (idx & 15) * 4;   // rr = n-local, cc = k-local
      unsigned short h[4], l[4];
#pragma unroll
      for (int q = 0; q < 4; ++q) {
        float f = Ts[cc + q][rr];
        h[q] = f2bf(f);
        l[q] = f2bf(f - bf2f(h[q]));
      }
      size_t o = (size_t)(n0 + rr) * H_ + k0 + cc;
      *(ushort4*)(Wth + o) = make_ushort4(h[0], h[1], h[2], h[3]);
      *(ushort4*)(Wtl + o) = make_ushort4(l[0], l[1], l[2], l[3]);
    }
  } else {
    const int bb = b - 17408;   // 1024 blocks * 256 threads * 16 B = 4 MiB
    ((float4*)G)[bb * 256 + t] = (float4){0.f, 0.f, 0.f, 0.f};
  }
}

// ------- 3-term split-bf16 MFMA GEMM (R5 structure, XCD-swizzled grid) -------
// grid = dim3(64,16): bm = blockIdx.x, bn = blockIdx.y -> linear = bn*64+bm,
// XCD j (round-robin linear%8) holds bm = j mod 8 -> only 8 A panels per XCD
// instead of all 64 (R9 FETCH evidence: per-XCD A re-fetch was the overfetch).
// LDS: 128 rows x 32 ushorts, XOR-swizzle ((row>>1)&3) -> 0 conflicts (R2/R5).
__global__ __launch_bounds__(256, 4) void k_gemm3(
    const unsigned short* __restrict__ Ah, const unsigned short* __restrict__ Al,
    const unsigned short* __restrict__ Bh, const unsigned short* __restrict__ Bl,
    unsigned short* __restrict__ Eh, unsigned short* __restrict__ El) {
  __shared__ unsigned short sAh[128 * 32], sAl[128 * 32], sBh[128 * 32], sBl[128 * 32];
  const int t = threadIdx.x;
  const int bm = blockIdx.x, bn = blockIdx.y;   // swapped for XCD L2 locality
  const int lane = t & 63, wid = t >> 6;
  const int wm = wid >> 1, wn = wid & 1;
  const int l16 = lane & 15, quad = lane >> 4;

  const int rl = lane >> 2;                    // row within 16-row chunk
  const int gg = (lane & 3) ^ ((rl >> 1) & 3); // swizzled global 16B-group
  const int c0 = wid * 2, c1 = wid * 2 + 1;
  const unsigned short* gAh0 = Ah + (size_t)(bm * 128 + c0 * 16 + rl) * H_ + gg * 8;
  const unsigned short* gAh1 = Ah + (size_t)(bm * 128 + c1 * 16 + rl) * H_ + gg * 8;
  const unsigned short* gAl0 = Al + (size_t)(bm * 128 + c0 * 16 + rl) * H_ + gg * 8;
  const unsigned short* gAl1 = Al + (size_t)(bm * 128 + c1 * 16 + rl) * H_ + gg * 8;
  const unsigned short* gBh0 = Bh + (size_t)(bn * 128 + c0 * 16 + rl) * H_ + gg * 8;
  const unsigned short* gBh1 = Bh + (size_t)(bn * 128 + c1 * 16 + rl) * H_ + gg * 8;
  const unsigned short* gBl0 = Bl + (size_t)(bn * 128 + c0 * 16 + rl) * H_ + gg * 8;
  const unsigned short* gBl1 = Bl + (size_t)(bn * 128 + c1 * 16 + rl) * H_ + gg * 8;
  unsigned short* lA0 = sAh + c0 * 512;  // chunk = 16 rows * 32 ushorts = 1 KiB
  unsigned short* lA1 = sAh + c1 * 512;
  unsigned short* lAl0 = sAl + c0 * 512;
  unsigned short* lAl1 = sAl + c1 * 512;
  unsigned short* lB0 = sBh + c0 * 512;
  unsigned short* lB1 = sBh + c1 * 512;
  unsigned short* lBl0 = sBl + c0 * 512;
  unsigned short* lBl1 = sBl + c1 * 512;

  const int swz = ((l16 >> 1) & 3);
  const int colq = ((quad ^ swz) * 8);

  f32x4 acc[4][4];
#pragma unroll
  for (int i = 0; i < 4; ++i)
#pragma unroll
    for (int j = 0; j < 4; ++j) acc[i][j] = (f32x4)0.f;

  for (int k0 = 0; k0 < H_; k0 += 32) {
    __syncthreads();
    glds16(gAh0 + k0, lA0);
    glds16(gAh1 + k0, lA1);
    glds16(gAl0 + k0, lAl0);
    glds16(gAl1 + k0, lAl1);
    glds16(gBh0 + k0, lB0);
    glds16(gBh1 + k0, lB1);
    glds16(gBl0 + k0, lBl0);
    glds16(gBl1 + k0, lBl1);
    __syncthreads();

    bf16x8 ah[4], al[4], bh[4], bl[4];
#pragma unroll
    for (int i = 0; i < 4; ++i) {
      const int ra = (wm * 64 + i * 16 + l16) * 32;
      const int rb = (wn * 64 + i * 16 + l16) * 32;
      ah[i] = *(const bf16x8*)&sAh[ra + colq];
      al[i] = *(const bf16x8*)&sAl[ra + colq];
      bh[i] = *(const bf16x8*)&sBh[rb + colq];
      bl[i] = *(const bf16x8*)&sBl[rb + colq];
    }
#pragma unroll
    for (int i = 0; i < 4; ++i)
#pragma unroll
      for (int j = 0; j < 4; ++j) {
        acc[i][j] = __builtin_amdgcn_mfma_f32_16x16x32_bf16(ah[i], bh[j], acc[i][j], 0, 0, 0);
        acc[i][j] = __builtin_amdgcn_mfma_f32_16x16x32_bf16(ah[i], bl[j], acc[i][j], 0, 0, 0);
        acc[i][j] = __builtin_amdgcn_mfma_f32_16x16x32_bf16(al[i], bh[j], acc[i][j], 0, 0, 0);
      }
  }

#pragma unroll
  for (int i = 0; i < 4; ++i) {
    const int row0 = bm * 128 + wm * 64 + i * 16 + quad * 4;
#pragma unroll
    for (int j = 0; j < 4; ++j) {
      const int col = bn * 128 + wn * 64 + j * 16 + l16;
#pragma unroll
      for (int r = 0; r < 4; ++r) {
        float v = acc[i][j][r];
        unsigned short hh = f2bf(v);
        unsigned short ll = f2bf(v - bf2f(hh));
        Eh[(size_t)(row0 + r) * H_ + col] = hh;
        El[(size_t)(row0 + r) * H_ + col] = ll;
      }
    }
  }
}

// ---- MFMA Gram: G[c] += Eh*Eh^T + Eh*El^T + El*Eh^T; each block does TWO
//      256-wide K chunks (register accumulate) -> atomics halved vs (8,64). ----
__global__ __launch_bounds__(256, 4) void k_gram_mfma(
    const unsigned short* __restrict__ Eh, const unsigned short* __restrict__ El,
    float* __restrict__ G) {
  __shared__ unsigned short sH[128 * 32], sL[128 * 32];
  const int t = threadIdx.x;
  const int kc = blockIdx.x;   // 0..3, each covers K chunks 2*kc, 2*kc+1
  const int cc = blockIdx.y;   // capsule
  const int lane = t & 63, wid = t >> 6;
  const int wm = wid >> 1, wn = wid & 1;
  const int l16 = lane & 15, quad = lane >> 4;

  const int rl = lane >> 2;
  const int gg = (lane & 3) ^ ((rl >> 1) & 3);
  const int c0 = wid * 2, c1 = c0 + 1;
  const unsigned short* gH0 = Eh + (size_t)(cc * 128 + c0 * 16 + rl) * H_ + gg * 8;
  const unsigned short* gH1 = Eh + (size_t)(cc * 128 + c1 * 16 + rl) * H_ + gg * 8;
  const unsigned short* gL0 = El + (size_t)(cc * 128 + c0 * 16 + rl) * H_ + gg * 8;
  const unsigned short* gL1 = El + (size_t)(cc * 128 + c1 * 16 + rl) * H_ + gg * 8;
  unsigned short* lH0 = sH + c0 * 512;
  unsigned short* lH1 = sH + c1 * 512;
  unsigned short* lL0 = sL + c0 * 512;
  unsigned short* lL1 = sL + c1 * 512;

  const int swz = ((l16 >> 1) & 3);
  const int colq = ((quad ^ swz) * 8);

  f32x4 acc[4][4];
#pragma unroll
  for (int i = 0; i < 4; ++i)
#pragma unroll
    for (int j = 0; j < 4; ++j) acc[i][j] = (f32x4)0.f;

  const int kbeg = kc * 512;           // two 256-wide chunks = 512
  for (int k0 = kbeg; k0 < kbeg + 512; k0 += 32) {
    __syncthreads();
    glds16(gH0 + k0, lH0);
    glds16(gH1 + k0, lH1);
    glds16(gL0 + k0, lL0);
    glds16(gL1 + k0, lL1);
    __syncthreads();

    bf16x8 ah[4], al[4], bh[4], bl[4];
#pragma unroll
    for (int i = 0; i < 4; ++i) {
      const int ra = (wm * 64 + i * 16 + l16) * 32;
      const int rb = (wn * 64 + i * 16 + l16) * 32;
      ah[i] = *(const bf16x8*)&sH[ra + colq];
      al[i] = *(const bf16x8*)&sL[ra + colq];
      bh[i] = *(const bf16x8*)&sH[rb + colq];
      bl[i] = *(const bf16x8*)&sL[rb + colq];
    }
#pragma unroll
    for (int i = 0; i < 4; ++i)
#pragma unroll
      for (int j = 0; j < 4; ++j) {
        acc[i][j] = __builtin_amdgcn_mfma_f32_16x16x32_bf16(ah[i], bh[j], acc[i][j], 0, 0, 0);
        acc[i][j] = __builtin_amdgcn_mfma_f32_16x16x32_bf16(ah[i], bl[j], acc[i][j], 0, 0, 0);
        acc[i][j] = __builtin_amdgcn_mfma_f32_16x16x32_bf16(al[i], bh[j], acc[i][j], 0, 0, 0);
      }
  }

  float* Gc = G + (size_t)cc * S_ * S_;
#pragma unroll
  for (int i = 0; i < 4; ++i) {
    const int row0 = wm * 64 + i * 16 + quad * 4;
#pragma unroll
    for (int j = 0; j < 4; ++j) {
      const int col = wn * 64 + j * 16 + l16;
#pragma unroll
      for (int r = 0; r < 4; ++r)
        atomicAdd(&Gc[(row0 + r) * S_ + col], acc[i][j][r]);
    }
  }
}

// ---- fused routing + projection: each block redoes its capsule's routing ----
__global__ void k_out2(const unsigned short* __restrict__ Eh,
                       const unsigned short* __restrict__ El,
                       const float* __restrict__ G, float* __restrict__ out) {
  const int c = blockIdx.y;
  const int s = threadIdx.x & 127;
  __shared__ float dsh[128];
  __shared__ float red[128];
  __shared__ float wsh[128];
  const float* Gc = G + (size_t)c * S_ * S_;
  float b = 0.f;
  for (int it = 0; it < 3; ++it) {
    red[s] = b; __syncthreads();
    for (int off = 64; off > 0; off >>= 1) {
      if (s < off) red[s] = fmaxf(red[s], red[s + off]);
      __syncthreads();
    }
    float mx = red[0]; __syncthreads();
    float ev = expf(b - mx);
    red[s] = ev; __syncthreads();
    for (int off = 64; off > 0; off >>= 1) {
      if (s < off) red[s] = red[s] + red[s + off];
      __syncthreads();
    }
    float Z = red[0]; __syncthreads();
    float d = ev / Z;
    dsh[s] = d; __syncthreads();
    float y = 0.f;   // (G d)_s via symmetric-column reads
#pragma unroll 8
    for (int j = 0; j < S_; ++j) y = fmaf(Gc[j * S_ + s], dsh[j], y);
    red[s] = d * y; __syncthreads();
    for (int off = 64; off > 0; off >>= 1) {
      if (s < off) red[s] = red[s] + red[s + off];
      __syncthreads();
    }
    float sq = red[0]; __syncthreads();
    float coeff = sq / (1.f + sq) / sqrtf(sq + 1e-9f);
    if (it == 2) wsh[s] = coeff * d;
    else b += coeff * y;
  }
  __syncthreads();

  // projection: out[c,h] = sum_s wsh[s] * (Eh+El)[c,s,h], 2 h per thread
  const int h2 = blockIdx.x * 256 + threadIdx.x;   // dword index, grid.x = 4
  const unsigned* Ph = (const unsigned*)(Eh + (size_t)c * S_ * H_) + h2;
  const unsigned* Pl = (const unsigned*)(El + (size_t)c * S_ * H_) + h2;
  float a0 = 0.f, a1 = 0.f;
#pragma unroll 8
  for (int ss = 0; ss < S_; ++ss) {
    unsigned uh = Ph[(size_t)ss * (H_ / 2)];
    unsigned ul = Pl[(size_t)ss * (H_ / 2)];
    a0 = fmaf(wsh[ss], bf2f((unsigned short)uh) + bf2f((unsigned short)ul), a0);
    a1 = fmaf(wsh[ss], bf2f((unsigned short)(uh >> 16)) + bf2f((unsigned short)(ul >> 16)), a1);
  }
  ((float2*)(out + (size_t)c * H_))[h2] = make_float2(a0, a1);
}

extern "C" void kernel_launch(void* const* d_in, const int* in_sizes, int n_in,
                              void* d_out, int out_size, void* d_ws, size_t ws_size,
                              hipStream_t stream) {
  (void)in_sizes; (void)n_in; (void)out_size; (void)ws_size;
  const float* x = (const float*)d_in[0];
  const float* W = (const float*)d_in[1];
  float* out = (float*)d_out;
  char* ws = (char*)d_ws;

  unsigned short* xh  = (unsigned short*)(ws);                 // 32 MiB
  unsigned short* xl  = (unsigned short*)(ws + 33554432);      // 32 MiB
  unsigned short* Wth = (unsigned short*)(ws + 67108864);      // 8 MiB
  unsigned short* Wtl = (unsigned short*)(ws + 75497472);      // 8 MiB
  unsigned short* Eh  = (unsigned short*)(ws + 83886080);      // 32 MiB
  unsigned short* El  = (unsigned short*)(ws + 117440512);     // 32 MiB
  float*          G   = (float*)(ws + 150994944);              // 4 MiB

  k_split_all<<<dim3(18432), 256, 0, stream>>>(x, xh, xl, W, Wth, Wtl, G);
  k_gemm3<<<dim3(64, 16), 256, 0, stream>>>(xh, xl, Wth, Wtl, Eh, El);
  k_gram_mfma<<<dim3(4, 64), 256, 0, stream>>>(Eh, El, G);
  k_out2<<<dim3(4, 64), 256, 0, stream>>>(Eh, El, G, out);
}